// Round 5
// baseline (290.065 us; speedup 1.0000x reference)
//
#include <hip/hip_runtime.h>

#define KDIM 768
#define MANS 640      // L*B*T
#define VV   30000
#define SN   32       // vocab rows per strip block
#define NBLK 938      // ceil(30000/32)

typedef __attribute__((ext_vector_type(4)))  float  f32x4;
typedef __attribute__((ext_vector_type(16))) float  f32x16;
typedef __attribute__((ext_vector_type(8)))  __bf16 bf16x8;

__device__ __forceinline__ unsigned short f2bf(float f) {
    union { float f; unsigned int u; } v; v.f = f;
    unsigned int r = v.u + 0x7fffu + ((v.u >> 16) & 1u);  // RNE
    return (unsigned short)(r >> 16);
}

__device__ __forceinline__ void load_lds16(const unsigned short* g, unsigned short* l) {
    __builtin_amdgcn_global_load_lds(
        (__attribute__((address_space(1))) void*)(void*)g,
        (__attribute__((address_space(3))) void*)l,
        16, 0, 0);
}

// ===================== prep_small =====================
// blocks [0,144):   W[768][768] f32 -> Wt[k][d]=W[d][k] bf16
// blocks [144,304): c[m] = dot(answer[m], b)
__global__ __launch_bounds__(256) void prep_small(
    const float* __restrict__ W, const float* __restrict__ A,
    const float* __restrict__ b, unsigned short* __restrict__ Wt_bf,
    float* __restrict__ cvec)
{
    __shared__ float ts[64][65];
    const int blk = blockIdx.x;
    if (blk < 144) {
        int bx = (blk % 12) * 64, by = (blk / 12) * 64;
        int tx = threadIdx.x & 63, tg = threadIdx.x >> 6;
#pragma unroll
        for (int i = 0; i < 16; ++i) {
            int r = tg * 16 + i;
            ts[r][tx] = W[(long)(by + r) * KDIM + bx + tx];
        }
        __syncthreads();
#pragma unroll
        for (int i = 0; i < 16; ++i) {
            int r = tg * 16 + i;
            Wt_bf[(long)(bx + r) * KDIM + by + tx] = f2bf(ts[tx][r]);
        }
    } else {
        int row  = (blk - 144) * 4 + (threadIdx.x >> 6);
        int lane = threadIdx.x & 63;
        const float* ap = A + (long)row * KDIM;
        float s = 0.f;
#pragma unroll
        for (int i = 0; i < KDIM / 64; ++i) s += ap[i * 64 + lane] * b[i * 64 + lane];
#pragma unroll
        for (int off = 32; off; off >>= 1) s += __shfl_down(s, off, 64);
        if (lane == 0) cvec[row] = s;
    }
}

// ===================== a2 gemm (unchanged round-4 structure) =====================
// A2[m][k] = sum_d answer[m][d] * Wt[k][d], bf16 out.
__global__ __launch_bounds__(256) void gemm_a2(
    const float* __restrict__ Af, const unsigned short* __restrict__ Bp,
    unsigned short* __restrict__ outp)
{
    constexpr int TM = 64, TN = 128;
    __shared__ unsigned short sA[TM * 64];
    __shared__ unsigned short sB[TN * 64];

    const int t    = threadIdx.x;
    const int lane = t & 63;
    const int w    = t >> 6;
    const int wm   = w >> 1;
    const int wn   = w & 1;
    const int half = lane >> 5;
    const int col  = lane & 31;
    const long m0  = (long)blockIdx.x * TM;
    const long n0  = (long)blockIdx.y * TN;

    f32x16 acc[2];
    acc[0] = (f32x16)(0.f);
    acc[1] = (f32x16)(0.f);

    for (int k0 = 0; k0 < KDIM; k0 += 64) {
#pragma unroll
        for (int j = 0; j < 2; ++j) {
            int s   = (j * 4 + w) * 64 + lane;
            int row = s >> 3;
            int c   = (s & 7) ^ (row & 7);
            const float* g = Af + (m0 + row) * KDIM + k0 + c * 8;
            f32x4 v0 = ((const f32x4*)g)[0], v1 = ((const f32x4*)g)[1];
            ushort4 o0, o1;
            o0.x = f2bf(v0.x); o0.y = f2bf(v0.y); o0.z = f2bf(v0.z); o0.w = f2bf(v0.w);
            o1.x = f2bf(v1.x); o1.y = f2bf(v1.y); o1.z = f2bf(v1.z); o1.w = f2bf(v1.w);
            unsigned short* d = &sA[s * 8];
            ((ushort4*)d)[0] = o0; ((ushort4*)d)[1] = o1;
        }
#pragma unroll
        for (int j = 0; j < 4; ++j) {
            int s   = (j * 4 + w) * 64 + lane;
            int row = s >> 3;
            int c   = (s & 7) ^ (row & 7);
            load_lds16(Bp + (n0 + row) * KDIM + k0 + c * 8,
                       &sB[(j * 4 + w) * 64 * 8]);
        }
        __syncthreads();

#pragma unroll
        for (int g = 0; g < 4; ++g) {
            const int cg = g * 2 + half;
            int arow = wm * 32 + col;
            bf16x8 af = *(const bf16x8*)&sA[(arow * 8 + (cg ^ (arow & 7))) * 8];
#pragma unroll
            for (int fn = 0; fn < 2; ++fn) {
                int brow = wn * 64 + fn * 32 + col;
                bf16x8 bf = *(const bf16x8*)&sB[(brow * 8 + (cg ^ (brow & 7))) * 8];
                acc[fn] = __builtin_amdgcn_mfma_f32_32x32x16_bf16(
                    af, bf, acc[fn], 0, 0, 0);
            }
        }
        __syncthreads();
    }

#pragma unroll
    for (int fn = 0; fn < 2; ++fn) {
        long n = n0 + wn * 64 + fn * 32 + col;
#pragma unroll
        for (int rg = 0; rg < 16; ++rg) {
            long m = m0 + wm * 32 + (rg & 3) + 8 * (rg >> 2) + 4 * half;
            outp[m * KDIM + n] = f2bf(acc[fn][rg]);
        }
    }
}

// ===================== strip gemm: out = A2 @ vocab^T + c =====================
// One block owns 32 vocab rows: stage them (f32->bf16) into LDS ONCE, one
// barrier total, then a barrier-free loop over all 20 m-tiles. B frags from
// swizzled LDS (8-clk floor, no conflicts); A2 frags direct from global (L2).
// MFMA pairs (2 indep acc) break the dep chain.
__global__ __launch_bounds__(256) void gemm_strip(
    const unsigned short* __restrict__ A2, const float* __restrict__ vocab,
    const float* __restrict__ cvec, float* __restrict__ outp)
{
    __shared__ unsigned short sB[SN * KDIM];   // 48 KB

    const int t    = threadIdx.x;
    const int lane = t & 63;
    const int w    = t >> 6;
    const int col  = lane & 31;
    const int half = lane >> 5;
    const long n0  = (long)blockIdx.x * SN;

    // ---- stage: 32 rows x 96 16B-chunks, chunk swizzle c^(row&7) ----
    {
        int r  = t >> 3;      // 0..31
        int cl = t & 7;
        long grow = n0 + r; if (grow > VV - 1) grow = VV - 1;
        const float* gp = vocab + grow * KDIM;
        unsigned short* lrow = sB + r * KDIM;
#pragma unroll
        for (int j = 0; j < 12; ++j) {
            int c = cl + 8 * j;
            const float* g = gp + c * 8;
            f32x4 v0 = ((const f32x4*)g)[0], v1 = ((const f32x4*)g)[1];
            ushort4 o0, o1;
            o0.x = f2bf(v0.x); o0.y = f2bf(v0.y); o0.z = f2bf(v0.z); o0.w = f2bf(v0.w);
            o1.x = f2bf(v1.x); o1.y = f2bf(v1.y); o1.z = f2bf(v1.z); o1.w = f2bf(v1.w);
            unsigned short* d = lrow + ((c ^ (r & 7)) * 8);
            ((ushort4*)d)[0] = o0; ((ushort4*)d)[1] = o1;
        }
    }
    __syncthreads();   // the only barrier

    const long nout = n0 + col;
    const bool nok  = (nout < VV);

    // B frag for k-step s: row=col, chunk=2s+half, swizzled
    const unsigned short* bbase = sB + col * KDIM;

    // ---- 20 m-tiles; wave w takes {w, w+4, ..., w+16}: two pairs + one ----
#pragma unroll
    for (int p = 0; p < 2; ++p) {
        const long mA = (long)(w + 8 * p) * 32;
        const long mB = mA + 128;
        f32x16 accA = (f32x16)(0.f), accB = (f32x16)(0.f);
        const unsigned short* pa = A2 + (mA + col) * KDIM + half * 8;
        const unsigned short* pb = A2 + (mB + col) * KDIM + half * 8;
#pragma unroll 4
        for (int s = 0; s < 48; ++s) {
            bf16x8 bf = *(const bf16x8*)(bbase + (((2 * s + half) ^ (col & 7)) * 8));
            bf16x8 aA = *(const bf16x8*)(pa + s * 16);
            bf16x8 aB = *(const bf16x8*)(pb + s * 16);
            accA = __builtin_amdgcn_mfma_f32_32x32x16_bf16(aA, bf, accA, 0, 0, 0);
            accB = __builtin_amdgcn_mfma_f32_32x32x16_bf16(aB, bf, accB, 0, 0, 0);
        }
        if (nok) {
#pragma unroll
            for (int rg = 0; rg < 16; ++rg) {
                long mm = (rg & 3) + 8 * (rg >> 2) + 4 * half;
                outp[(mA + mm) * (long)VV + nout] = accA[rg] + cvec[mA + mm];
                outp[(mB + mm) * (long)VV + nout] = accB[rg] + cvec[mB + mm];
            }
        }
    }
    {   // last tile: w+16
        const long mA = (long)(w + 16) * 32;
        f32x16 acc = (f32x16)(0.f);
        const unsigned short* pa = A2 + (mA + col) * KDIM + half * 8;
#pragma unroll 4
        for (int s = 0; s < 48; ++s) {
            bf16x8 bf = *(const bf16x8*)(bbase + (((2 * s + half) ^ (col & 7)) * 8));
            bf16x8 aA = *(const bf16x8*)(pa + s * 16);
            acc = __builtin_amdgcn_mfma_f32_32x32x16_bf16(aA, bf, acc, 0, 0, 0);
        }
        if (nok) {
#pragma unroll
            for (int rg = 0; rg < 16; ++rg) {
                long mm = (rg & 3) + 8 * (rg >> 2) + 4 * half;
                outp[(mA + mm) * (long)VV + nout] = acc[rg] + cvec[mA + mm];
            }
        }
    }
}

extern "C" void kernel_launch(void* const* d_in, const int* in_sizes, int n_in,
                              void* d_out, int out_size, void* d_ws, size_t ws_size,
                              hipStream_t stream) {
    const float* answer = (const float*)d_in[0];   // [640][768] f32
    const float* vocab  = (const float*)d_in[1];   // [30000][768] f32
    const float* W      = (const float*)d_in[2];   // [768][768] f32
    const float* bvec   = (const float*)d_in[3];   // [768] f32

    char* ws = (char*)d_ws;
    unsigned short* Wt_bf = (unsigned short*)ws;                    // 1,179,648 B
    unsigned short* A2_bf = (unsigned short*)(ws + 1179648);        //   983,040 B
    float*          cptr  = (float*)(ws + 1179648 + 983040);        //     2,560 B

    // 1. Wt = W^T (bf16), c = answer @ b
    prep_small<<<304, 256, 0, stream>>>(W, answer, bvec, Wt_bf, cptr);

    // 2. A2[m][k] = sum_d answer[m][d] * Wt[k][d]
    gemm_a2<<<dim3(MANS / 64, KDIM / 128), 256, 0, stream>>>(answer, Wt_bf, A2_bf);

    // 3. out[m][v] = sum_k A2[m][k] * vocab_bf16(v,k) + c[m]; strip-resident LDS
    gemm_strip<<<NBLK, 256, 0, stream>>>(A2_bf, vocab, cptr, (float*)d_out);
}